// Round 5
// baseline (118.818 us; speedup 1.0000x reference)
//
#include <hip/hip_runtime.h>
#include <math.h>

// Problem constants (from reference): B=4, N=4096, H=16, D=64
#define BB 4
#define NN 4096
#define HH 16
#define DD 64

// One chunk per thread: 4 groups, 28 float4 loads, all forced in flight.
#define GRID_BLOCKS 4096
#define BLOCK_THREADS 256
#define GSTRIDE ((GRID_BLOCKS * BLOCK_THREADS) >> 4)   // 65536 groups
#define TOTAL_GROUPS (BB * NN * HH)                     // 262144
#define UNROLL (TOTAL_GROUPS / GSTRIDE)                 // 4 — whole thread's work

// clang-native 16B vector: works with __builtin_nontemporal_store / asm "v"
typedef float f32x4 __attribute__((ext_vector_type(4)));

// min 3 waves/EU -> VGPR cap ~168. The 28-operand pin-asm below forces
// 112 VGPRs of load payload simultaneously live — liveness, not scheduler
// heuristics, so RA cannot serialize the loads (R1/R4 failure mode).
__global__ __launch_bounds__(BLOCK_THREADS, 3) void hsa_kernel(
    const float* __restrict__ Qp,
    const float* __restrict__ Kp,
    const float* __restrict__ Vp,
    const float* __restrict__ Kc,
    const float* __restrict__ Vc,
    float* __restrict__ out)
{
    const float sm_scale = 0.125f;              // 1/sqrt(64)

    const int tid    = blockIdx.x * blockDim.x + threadIdx.x;
    const int lane4  = tid & 15;                // lane within 16-lane group
    const int gstart = tid >> 4;

    f32x4 q[UNROLL], kp[UNROLL], kc0[UNROLL], kc1[UNROLL];
    f32x4 vp[UNROLL], vc0[UNROLL], vc1[UNROLL];
    int poff[UNROLL];

    // ---- issue ALL 28 loads ----
    #pragma unroll
    for (int j = 0; j < UNROLL; ++j) {
        const int g = gstart + j * GSTRIDE;
        const int h = g & (HH - 1);
        const int n = (g >> 4) & (NN - 1);
        const int b = g >> 16;
        const int p = g * DD + lane4 * 4;
        const int c0 = (((b * 2 * NN + 2 * n) * HH + h) * DD) + lane4 * 4;
        const int c1 = c0 + HH * DD;
        poff[j] = p;
        q[j]   = *reinterpret_cast<const f32x4*>(Qp + p);
        kp[j]  = *reinterpret_cast<const f32x4*>(Kp + p);
        kc0[j] = *reinterpret_cast<const f32x4*>(Kc + c0);
        kc1[j] = *reinterpret_cast<const f32x4*>(Kc + c1);
        vp[j]  = *reinterpret_cast<const f32x4*>(Vp + p);
        vc0[j] = *reinterpret_cast<const f32x4*>(Vc + c0);
        vc1[j] = *reinterpret_cast<const f32x4*>(Vc + c1);
    }

    // Pin: all 28 results must be live in VGPRs at this single point.
    asm volatile("" ::
        "v"(q[0]),   "v"(q[1]),   "v"(q[2]),   "v"(q[3]),
        "v"(kp[0]),  "v"(kp[1]),  "v"(kp[2]),  "v"(kp[3]),
        "v"(kc0[0]), "v"(kc0[1]), "v"(kc0[2]), "v"(kc0[3]),
        "v"(kc1[0]), "v"(kc1[1]), "v"(kc1[2]), "v"(kc1[3]),
        "v"(vp[0]),  "v"(vp[1]),  "v"(vp[2]),  "v"(vp[3]),
        "v"(vc0[0]), "v"(vc0[1]), "v"(vc0[2]), "v"(vc0[3]),
        "v"(vc1[0]), "v"(vc1[1]), "v"(vc1[2]), "v"(vc1[3]));
    __builtin_amdgcn_sched_barrier(0);

    // ---- compute (stall-free: all data resident) ----
    float s0[UNROLL], s1[UNROLL], s2[UNROLL];
    #pragma unroll
    for (int j = 0; j < UNROLL; ++j) {
        s0[j] = q[j].x*kp[j].x  + q[j].y*kp[j].y  + q[j].z*kp[j].z  + q[j].w*kp[j].w;
        s1[j] = q[j].x*kc0[j].x + q[j].y*kc0[j].y + q[j].z*kc0[j].z + q[j].w*kc0[j].w;
        s2[j] = q[j].x*kc1[j].x + q[j].y*kc1[j].y + q[j].z*kc1[j].z + q[j].w*kc1[j].w;
    }

    // 12 independent butterfly chains interleaved
    #pragma unroll
    for (int m = 8; m >= 1; m >>= 1) {
        #pragma unroll
        for (int j = 0; j < UNROLL; ++j) {
            s0[j] += __shfl_xor(s0[j], m);
            s1[j] += __shfl_xor(s1[j], m);
            s2[j] += __shfl_xor(s2[j], m);
        }
    }

    #pragma unroll
    for (int j = 0; j < UNROLL; ++j) {
        const float t0 = s0[j] * sm_scale;
        const float t1 = s1[j] * sm_scale;
        const float t2 = s2[j] * sm_scale;
        const float mx = fmaxf(fmaxf(t0, t1), t2);
        const float e0 = __expf(t0 - mx);
        const float e1 = __expf(t1 - mx);
        const float e2 = __expf(t2 - mx);
        const float inv = 1.0f / (e0 + e1 + e2 + 1e-9f);
        const float w0 = e0 * inv, w1 = e1 * inv, w2 = e2 * inv;

        f32x4 o;
        o.x = w0*vp[j].x + w1*vc0[j].x + w2*vc1[j].x;
        o.y = w0*vp[j].y + w1*vc0[j].y + w2*vc1[j].y;
        o.z = w0*vp[j].z + w1*vc0[j].z + w2*vc1[j].z;
        o.w = w0*vp[j].w + w1*vc0[j].w + w2*vc1[j].w;
        // write-once output: nontemporal, don't displace inputs from L2/L3
        __builtin_nontemporal_store(o, reinterpret_cast<f32x4*>(out + poff[j]));
    }
}

extern "C" void kernel_launch(void* const* d_in, const int* in_sizes, int n_in,
                              void* d_out, int out_size, void* d_ws, size_t ws_size,
                              hipStream_t stream) {
    const float* Qp = (const float*)d_in[0];
    const float* Kp = (const float*)d_in[1];
    const float* Vp = (const float*)d_in[2];
    const float* Kc = (const float*)d_in[3];
    const float* Vc = (const float*)d_in[4];
    float* out = (float*)d_out;

    dim3 grid(GRID_BLOCKS), block(BLOCK_THREADS);
    hipLaunchKernelGGL(hsa_kernel, grid, block, 0, stream, Qp, Kp, Vp, Kc, Vc, out);
}

// Round 6
// 100.264 us; speedup vs baseline: 1.1851x; 1.1851x over previous
//
#include <hip/hip_runtime.h>
#include <math.h>

// Problem constants (from reference): B=4, N=4096, H=16, D=64
#define BB 4
#define NN 4096
#define HH 16
#define DD 64

#define GRID_BLOCKS 2048
#define BLOCK_THREADS 256
#define GSTRIDE ((GRID_BLOCKS * BLOCK_THREADS) >> 4)   // 32768 groups
#define TOTAL_GROUPS (BB * NN * HH)                     // 262144
#define ITERS (TOTAL_GROUPS / GSTRIDE)                  // 8
#define UNROLL 4                                        // groups per chunk

// clang-native 16B vector: works with nontemporal load/store builtins
typedef float f32x4 __attribute__((ext_vector_type(4)));

#define NTLOAD(p) __builtin_nontemporal_load(reinterpret_cast<const f32x4*>(p))

// R1-R5 established: NOT latency-bound (plateau invariant to occupancy
// 37-63%, VGPR 24-64, unroll 1-4). Hypothesis: L3 serves a fixed 47% of
// reads at only ~2.6 TB/s, capping total at 5.5 TB/s while HBM idles at
// 46%. NT loads stop L2/L3 allocation -> serve reads from HBM (2.2x
// headroom). Falsifiable: FETCH_SIZE must jump 229 MB -> ~500 MB.
__global__ __launch_bounds__(BLOCK_THREADS) void hsa_kernel(
    const float* __restrict__ Qp,
    const float* __restrict__ Kp,
    const float* __restrict__ Vp,
    const float* __restrict__ Kc,
    const float* __restrict__ Vc,
    float* __restrict__ out)
{
    const float sm_scale = 0.125f;              // 1/sqrt(64)

    const int tid    = blockIdx.x * blockDim.x + threadIdx.x;
    const int lane4  = tid & 15;                // lane within 16-lane group
    const int gstart = tid >> 4;

    #pragma unroll
    for (int k = 0; k < ITERS; k += UNROLL) {
        f32x4 q[UNROLL], kp[UNROLL], kc0[UNROLL], kc1[UNROLL];
        f32x4 vp[UNROLL], vc0[UNROLL], vc1[UNROLL];
        int poff[UNROLL];

        #pragma unroll
        for (int j = 0; j < UNROLL; ++j) {
            const int g = gstart + (k + j) * GSTRIDE;
            const int h = g & (HH - 1);
            const int n = (g >> 4) & (NN - 1);
            const int b = g >> 16;
            const int p = g * DD + lane4 * 4;
            const int c0 = (((b * 2 * NN + 2 * n) * HH + h) * DD) + lane4 * 4;
            const int c1 = c0 + HH * DD;
            poff[j] = p;
            q[j]   = NTLOAD(Qp + p);
            kp[j]  = NTLOAD(Kp + p);
            kc0[j] = NTLOAD(Kc + c0);
            kc1[j] = NTLOAD(Kc + c1);
            vp[j]  = NTLOAD(Vp + p);
            vc0[j] = NTLOAD(Vc + c0);
            vc1[j] = NTLOAD(Vc + c1);
        }

        float s0[UNROLL], s1[UNROLL], s2[UNROLL];
        #pragma unroll
        for (int j = 0; j < UNROLL; ++j) {
            s0[j] = q[j].x*kp[j].x  + q[j].y*kp[j].y  + q[j].z*kp[j].z  + q[j].w*kp[j].w;
            s1[j] = q[j].x*kc0[j].x + q[j].y*kc0[j].y + q[j].z*kc0[j].z + q[j].w*kc0[j].w;
            s2[j] = q[j].x*kc1[j].x + q[j].y*kc1[j].y + q[j].z*kc1[j].z + q[j].w*kc1[j].w;
        }

        #pragma unroll
        for (int m = 8; m >= 1; m >>= 1) {
            #pragma unroll
            for (int j = 0; j < UNROLL; ++j) {
                s0[j] += __shfl_xor(s0[j], m);
                s1[j] += __shfl_xor(s1[j], m);
                s2[j] += __shfl_xor(s2[j], m);
            }
        }

        #pragma unroll
        for (int j = 0; j < UNROLL; ++j) {
            const float t0 = s0[j] * sm_scale;
            const float t1 = s1[j] * sm_scale;
            const float t2 = s2[j] * sm_scale;
            const float mx = fmaxf(fmaxf(t0, t1), t2);
            const float e0 = __expf(t0 - mx);
            const float e1 = __expf(t1 - mx);
            const float e2 = __expf(t2 - mx);
            const float inv = 1.0f / (e0 + e1 + e2 + 1e-9f);
            const float w0 = e0 * inv, w1 = e1 * inv, w2 = e2 * inv;

            f32x4 o;
            o.x = w0*vp[j].x + w1*vc0[j].x + w2*vc1[j].x;
            o.y = w0*vp[j].y + w1*vc0[j].y + w2*vc1[j].y;
            o.z = w0*vp[j].z + w1*vc0[j].z + w2*vc1[j].z;
            o.w = w0*vp[j].w + w1*vc0[j].w + w2*vc1[j].w;
            // write-once output stays nontemporal
            __builtin_nontemporal_store(o, reinterpret_cast<f32x4*>(out + poff[j]));
        }
    }
}

extern "C" void kernel_launch(void* const* d_in, const int* in_sizes, int n_in,
                              void* d_out, int out_size, void* d_ws, size_t ws_size,
                              hipStream_t stream) {
    const float* Qp = (const float*)d_in[0];
    const float* Kp = (const float*)d_in[1];
    const float* Vp = (const float*)d_in[2];
    const float* Kc = (const float*)d_in[3];
    const float* Vc = (const float*)d_in[4];
    float* out = (float*)d_out;

    dim3 grid(GRID_BLOCKS), block(BLOCK_THREADS);
    hipLaunchKernelGGL(hsa_kernel, grid, block, 0, stream, Qp, Kp, Vp, Kc, Vc, out);
}

// Round 7
// 97.266 us; speedup vs baseline: 1.2216x; 1.0308x over previous
//
#include <hip/hip_runtime.h>
#include <math.h>

// Problem constants (from reference): B=4, N=4096, H=16, D=64
#define BB 4
#define NN 4096
#define HH 16
#define DD 64

// Finer-grained decomposition: 8192 blocks x 256 thr, 16 lanes/group ->
// each thread owns exactly UNROLL=2 groups, no outer loop. 32 blocks/CU
// gives the dispatcher backfill slack to smooth the L3-miss straggler tail
// (R6: only 8 blocks/CU, one generation, OccupancyPercent 47%).
#define GRID_BLOCKS 8192
#define BLOCK_THREADS 256
#define GSTRIDE ((GRID_BLOCKS * BLOCK_THREADS) >> 4)   // 131072 groups
#define TOTAL_GROUPS (BB * NN * HH)                     // 262144
#define UNROLL (TOTAL_GROUPS / GSTRIDE)                 // 2

// clang-native 16B vector: works with nontemporal load/store builtins
typedef float f32x4 __attribute__((ext_vector_type(4)));

#define NTLOAD(p) __builtin_nontemporal_load(reinterpret_cast<const f32x4*>(p))

__global__ __launch_bounds__(BLOCK_THREADS) void hsa_kernel(
    const float* __restrict__ Qp,
    const float* __restrict__ Kp,
    const float* __restrict__ Vp,
    const float* __restrict__ Kc,
    const float* __restrict__ Vc,
    float* __restrict__ out)
{
    const float sm_scale = 0.125f;              // 1/sqrt(64)

    const int tid    = blockIdx.x * blockDim.x + threadIdx.x;
    const int lane4  = tid & 15;                // lane within 16-lane group
    const int gstart = tid >> 4;

    f32x4 q[UNROLL], kp[UNROLL], kc0[UNROLL], kc1[UNROLL];
    f32x4 vp[UNROLL], vc0[UNROLL], vc1[UNROLL];
    int poff[UNROLL];

    #pragma unroll
    for (int j = 0; j < UNROLL; ++j) {
        const int g = gstart + j * GSTRIDE;
        const int h = g & (HH - 1);
        const int n = (g >> 4) & (NN - 1);
        const int b = g >> 16;
        const int p = g * DD + lane4 * 4;
        const int c0 = (((b * 2 * NN + 2 * n) * HH + h) * DD) + lane4 * 4;
        const int c1 = c0 + HH * DD;
        poff[j] = p;
        q[j]   = NTLOAD(Qp + p);
        kp[j]  = NTLOAD(Kp + p);
        kc0[j] = NTLOAD(Kc + c0);
        kc1[j] = NTLOAD(Kc + c1);
        vp[j]  = NTLOAD(Vp + p);
        vc0[j] = NTLOAD(Vc + c0);
        vc1[j] = NTLOAD(Vc + c1);
    }

    float s0[UNROLL], s1[UNROLL], s2[UNROLL];
    #pragma unroll
    for (int j = 0; j < UNROLL; ++j) {
        s0[j] = q[j].x*kp[j].x  + q[j].y*kp[j].y  + q[j].z*kp[j].z  + q[j].w*kp[j].w;
        s1[j] = q[j].x*kc0[j].x + q[j].y*kc0[j].y + q[j].z*kc0[j].z + q[j].w*kc0[j].w;
        s2[j] = q[j].x*kc1[j].x + q[j].y*kc1[j].y + q[j].z*kc1[j].z + q[j].w*kc1[j].w;
    }

    #pragma unroll
    for (int m = 8; m >= 1; m >>= 1) {
        #pragma unroll
        for (int j = 0; j < UNROLL; ++j) {
            s0[j] += __shfl_xor(s0[j], m);
            s1[j] += __shfl_xor(s1[j], m);
            s2[j] += __shfl_xor(s2[j], m);
        }
    }

    #pragma unroll
    for (int j = 0; j < UNROLL; ++j) {
        const float t0 = s0[j] * sm_scale;
        const float t1 = s1[j] * sm_scale;
        const float t2 = s2[j] * sm_scale;
        const float mx = fmaxf(fmaxf(t0, t1), t2);
        const float e0 = __expf(t0 - mx);
        const float e1 = __expf(t1 - mx);
        const float e2 = __expf(t2 - mx);
        const float inv = 1.0f / (e0 + e1 + e2 + 1e-9f);
        const float w0 = e0 * inv, w1 = e1 * inv, w2 = e2 * inv;

        f32x4 o;
        o.x = w0*vp[j].x + w1*vc0[j].x + w2*vc1[j].x;
        o.y = w0*vp[j].y + w1*vc0[j].y + w2*vc1[j].y;
        o.z = w0*vp[j].z + w1*vc0[j].z + w2*vc1[j].z;
        o.w = w0*vp[j].w + w1*vc0[j].w + w2*vc1[j].w;
        // write-once output stays nontemporal
        __builtin_nontemporal_store(o, reinterpret_cast<f32x4*>(out + poff[j]));
    }
}

extern "C" void kernel_launch(void* const* d_in, const int* in_sizes, int n_in,
                              void* d_out, int out_size, void* d_ws, size_t ws_size,
                              hipStream_t stream) {
    const float* Qp = (const float*)d_in[0];
    const float* Kp = (const float*)d_in[1];
    const float* Vp = (const float*)d_in[2];
    const float* Kc = (const float*)d_in[3];
    const float* Vc = (const float*)d_in[4];
    float* out = (float*)d_out;

    dim3 grid(GRID_BLOCKS), block(BLOCK_THREADS);
    hipLaunchKernelGGL(hsa_kernel, grid, block, 0, stream, Qp, Kp, Vp, Kc, Vc, out);
}

// Round 8
// 91.249 us; speedup vs baseline: 1.3021x; 1.0659x over previous
//
#include <hip/hip_runtime.h>
#include <math.h>

// Problem constants (from reference): B=4, N=4096, H=16, D=64
#define BB 4
#define NN 4096
#define HH 16
#define DD 64

// Finest-grained decomposition: 16384 blocks x 256 thr, 16 lanes/group ->
// each thread owns exactly ONE group (7 float4 loads). 64 blocks/CU = 8
// backfill generations smooths the L3-miss straggler tail (R6->R7: going
// 8->32 blocks/CU gave +3%; this is the same lever's last notch).
#define GRID_BLOCKS 16384
#define BLOCK_THREADS 256
#define TOTAL_GROUPS (BB * NN * HH)                     // 262144

// clang-native 16B vector: works with nontemporal load/store builtins
typedef float f32x4 __attribute__((ext_vector_type(4)));

#define NTLOAD(p) __builtin_nontemporal_load(reinterpret_cast<const f32x4*>(p))

__global__ __launch_bounds__(BLOCK_THREADS) void hsa_kernel(
    const float* __restrict__ Qp,
    const float* __restrict__ Kp,
    const float* __restrict__ Vp,
    const float* __restrict__ Kc,
    const float* __restrict__ Vc,
    float* __restrict__ out)
{
    const float sm_scale = 0.125f;              // 1/sqrt(64)

    const int tid   = blockIdx.x * blockDim.x + threadIdx.x;
    const int lane4 = tid & 15;                 // lane within 16-lane group
    const int g     = tid >> 4;                 // one group per thread

    const int h = g & (HH - 1);
    const int n = (g >> 4) & (NN - 1);
    const int b = g >> 16;
    const int p  = g * DD + lane4 * 4;
    const int c0 = (((b * 2 * NN + 2 * n) * HH + h) * DD) + lane4 * 4;
    const int c1 = c0 + HH * DD;

    const f32x4 q   = NTLOAD(Qp + p);
    const f32x4 kp  = NTLOAD(Kp + p);
    const f32x4 kc0 = NTLOAD(Kc + c0);
    const f32x4 kc1 = NTLOAD(Kc + c1);
    const f32x4 vp  = NTLOAD(Vp + p);
    const f32x4 vc0 = NTLOAD(Vc + c0);
    const f32x4 vc1 = NTLOAD(Vc + c1);

    float s0 = q.x*kp.x  + q.y*kp.y  + q.z*kp.z  + q.w*kp.w;
    float s1 = q.x*kc0.x + q.y*kc0.y + q.z*kc0.z + q.w*kc0.w;
    float s2 = q.x*kc1.x + q.y*kc1.y + q.z*kc1.z + q.w*kc1.w;

    #pragma unroll
    for (int m = 8; m >= 1; m >>= 1) {
        s0 += __shfl_xor(s0, m);
        s1 += __shfl_xor(s1, m);
        s2 += __shfl_xor(s2, m);
    }

    s0 *= sm_scale; s1 *= sm_scale; s2 *= sm_scale;
    const float mx = fmaxf(fmaxf(s0, s1), s2);
    const float e0 = __expf(s0 - mx);
    const float e1 = __expf(s1 - mx);
    const float e2 = __expf(s2 - mx);
    const float inv = 1.0f / (e0 + e1 + e2 + 1e-9f);
    const float w0 = e0 * inv, w1 = e1 * inv, w2 = e2 * inv;

    f32x4 o;
    o.x = w0*vp.x + w1*vc0.x + w2*vc1.x;
    o.y = w0*vp.y + w1*vc0.y + w2*vc1.y;
    o.z = w0*vp.z + w1*vc0.z + w2*vc1.z;
    o.w = w0*vp.w + w1*vc0.w + w2*vc1.w;
    // write-once output stays nontemporal
    __builtin_nontemporal_store(o, reinterpret_cast<f32x4*>(out + p));
}

extern "C" void kernel_launch(void* const* d_in, const int* in_sizes, int n_in,
                              void* d_out, int out_size, void* d_ws, size_t ws_size,
                              hipStream_t stream) {
    const float* Qp = (const float*)d_in[0];
    const float* Kp = (const float*)d_in[1];
    const float* Vp = (const float*)d_in[2];
    const float* Kc = (const float*)d_in[3];
    const float* Vc = (const float*)d_in[4];
    float* out = (float*)d_out;

    dim3 grid(GRID_BLOCKS), block(BLOCK_THREADS);
    hipLaunchKernelGGL(hsa_kernel, grid, block, 0, stream, Qp, Kp, Vp, Kc, Vc, out);
}